// Round 3
// baseline (157.680 us; speedup 1.0000x reference)
//
#include <hip/hip_runtime.h>
#include <cstdint>
#include <cstddef>

#define ALPHA_ 0.25f
#define CLAMP_ 1e-4f

static constexpr int BLK = 256;
static constexpr int MAXB = 2048;

// ws layout (bytes). Every region is written before it is read on every call,
// so no initialization kernel is needed (poison-safe).
static constexpr size_t OFF_BCONF = 0;        // bconf[MAXB][32] f32 (256 KB)
static constexpr size_t OFF_BVMAX = 262144;   // bvmax[MAXB][32] f32 (256 KB)
static constexpr size_t OFF_CONF = 524288;    // conf[32] f32
static constexpr size_t OFF_VMAX = 524416;    // vmax[32] f32
static constexpr size_t OFF_PART = 524544;    // partial[MAXB] f32 (8 KB)
static constexpr size_t OFF_BITS = 1048576;   // maskbits[N] u32 (4 MB @ N=1e6)

__device__ inline unsigned int mask_from_row(const int* __restrict__ boxes, size_t i) {
    const int4* row = (const int4*)(boxes + i * 32);
    unsigned int m = 0u;
#pragma unroll
    for (int q = 0; q < 8; ++q) {
        int4 v = row[q];
        m |= (v.x > 0 ? 1u : 0u) << (4 * q + 0);
        m |= (v.y > 0 ? 1u : 0u) << (4 * q + 1);
        m |= (v.z > 0 ? 1u : 0u) << (4 * q + 2);
        m |= (v.w > 0 ? 1u : 0u) << (4 * q + 3);
    }
    return m;
}

// Pass 1: flat, fully-coalesced int4 stream over boxes. Lane group of 8 covers one
// row; 3 shfl_xor OR-steps assemble the row's 32-bit mask; thread keeps max for its
// 4 fixed columns only (4 VGPRs).
#define PROC1(a, s, idx, act)                                                     \
    {                                                                             \
        unsigned int nib = (unsigned int)((a).x > 0) |                            \
                           ((unsigned int)((a).y > 0) << 1) |                     \
                           ((unsigned int)((a).z > 0) << 2) |                     \
                           ((unsigned int)((a).w > 0) << 3);                      \
        unsigned int mm = nib << (4 * q);                                         \
        mm |= (unsigned int)__shfl_xor((int)mm, 1);                               \
        mm |= (unsigned int)__shfl_xor((int)mm, 2);                               \
        mm |= (unsigned int)__shfl_xor((int)mm, 4);                               \
        if (WRITEBITS && (act) && q == 0) maskbits[(idx) >> 3] = mm;              \
        c0 = fmaxf(c0, (nib & 1u) ? (s) : 0.0f);                                 \
        c1 = fmaxf(c1, (nib & 2u) ? (s) : 0.0f);                                 \
        c2 = fmaxf(c2, (nib & 4u) ? (s) : 0.0f);                                 \
        c3 = fmaxf(c3, (nib & 8u) ? (s) : 0.0f);                                 \
    }

template <bool WRITEBITS>
__global__ void __launch_bounds__(BLK) k_pass1(const int4* __restrict__ boxes4,
                                               const float* __restrict__ scores,
                                               unsigned int* __restrict__ maskbits,
                                               float* __restrict__ bconf, size_t total4) {
    __shared__ unsigned int sconf[32];
    const int t = threadIdx.x;
    if (t < 32) sconf[t] = 0u;
    __syncthreads();
    const int lane = t & 63;
    const int q = lane & 7;  // this thread owns columns 4q..4q+3
    float c0 = 0.0f, c1 = 0.0f, c2 = 0.0f, c3 = 0.0f;
    const size_t stride = (size_t)gridDim.x * BLK;
    size_t wb = (size_t)blockIdx.x * BLK + (size_t)(t - lane);  // wave-uniform base
    // main: 4 wave-iterations per trip, all lanes active -> 8 loads in flight
    for (; wb + 3 * stride + 64 <= total4; wb += 4 * stride) {
        const size_t i0 = wb + lane, i1 = i0 + stride, i2 = i1 + stride, i3 = i2 + stride;
        int4 a0 = boxes4[i0];
        int4 a1 = boxes4[i1];
        int4 a2 = boxes4[i2];
        int4 a3 = boxes4[i3];
        float s0 = scores[i0 >> 3];
        float s1 = scores[i1 >> 3];
        float s2 = scores[i2 >> 3];
        float s3 = scores[i3 >> 3];
        PROC1(a0, s0, i0, true)
        PROC1(a1, s1, i1, true)
        PROC1(a2, s2, i2, true)
        PROC1(a3, s3, i3, true)
    }
    // tail: predicated lanes, wave-uniform trip count
    for (; wb < total4; wb += stride) {
        const size_t i = wb + lane;
        const bool act = i < total4;
        int4 a = {0, 0, 0, 0};
        float s = 0.0f;
        if (act) {
            a = boxes4[i];
            s = scores[i >> 3];
        }
        PROC1(a, s, i, act)
    }
    // butterfly across the 8 row-groups in the wave (partners share q)
#pragma unroll
    for (int off = 8; off < 64; off <<= 1) {
        c0 = fmaxf(c0, __shfl_xor(c0, off));
        c1 = fmaxf(c1, __shfl_xor(c1, off));
        c2 = fmaxf(c2, __shfl_xor(c2, off));
        c3 = fmaxf(c3, __shfl_xor(c3, off));
    }
    if (lane < 8) {  // q == lane
        atomicMax(&sconf[4 * q + 0], __float_as_uint(c0));
        atomicMax(&sconf[4 * q + 1], __float_as_uint(c1));
        atomicMax(&sconf[4 * q + 2], __float_as_uint(c2));
        atomicMax(&sconf[4 * q + 3], __float_as_uint(c3));
    }
    __syncthreads();
    if (t < 32) bconf[(size_t)blockIdx.x * 32 + t] = __uint_as_float(sconf[t]);
}

// 1-block reducer: max over nb rows of src[nb][32] -> dst[32]. Contention-free
// replacement for the 65K-global-atomic funnel.
__global__ void __launch_bounds__(BLK) k_redmax(const float* __restrict__ src,
                                                float* __restrict__ dst, int nb) {
    __shared__ unsigned int sm[32];
    const int t = threadIdx.x;
    if (t < 32) sm[t] = 0u;
    __syncthreads();
    const int g = t & 31;
    float m = 0.0f;
    for (int b = t >> 5; b < nb; b += BLK / 32) m = fmaxf(m, src[(size_t)b * 32 + g]);
    atomicMax(&sm[g], __float_as_uint(m));
    __syncthreads();
    if (t < 32) dst[t] = __uint_as_float(sm[t]);
}

// Pass 2: vmax[g] = max over masked i of exp(conf[g]*log(s_i)) * iou_i.
template <bool USEBITS>
__global__ void __launch_bounds__(BLK) k_pass2(const unsigned int* __restrict__ maskbits,
                                               const int* __restrict__ boxes,
                                               const float* __restrict__ scores,
                                               const float* __restrict__ ious,
                                               const float* __restrict__ conf,
                                               float* __restrict__ bvmax, int n) {
    __shared__ float scf[32];
    __shared__ unsigned int svm[32];
    const int t = threadIdx.x;
    if (t < 32) {
        scf[t] = conf[t];
        svm[t] = 0u;
    }
    __syncthreads();
    float cf[32], vm[32];
#pragma unroll
    for (int g = 0; g < 32; ++g) {
        cf[g] = scf[g];
        vm[g] = 0.0f;
    }
    const size_t stride = (size_t)gridDim.x * BLK;
    for (size_t i = (size_t)blockIdx.x * BLK + t; i < (size_t)n; i += stride) {
        unsigned int m = USEBITS ? maskbits[i] : mask_from_row(boxes, i);
        float ls = __logf(scores[i]);
        float iou = ious[i];
#pragma unroll
        for (int g = 0; g < 32; ++g) {
            float v = __expf(cf[g] * ls) * iou;
            vm[g] = fmaxf(vm[g], ((m >> g) & 1u) ? v : 0.0f);
        }
    }
    // one butterfly per thread (not per row)
#pragma unroll
    for (int g = 0; g < 32; ++g) {
#pragma unroll
        for (int off = 32; off > 0; off >>= 1) vm[g] = fmaxf(vm[g], __shfl_xor(vm[g], off));
    }
    if ((t & 63) == 0) {
#pragma unroll
        for (int g = 0; g < 32; ++g) atomicMax(&svm[g], __float_as_uint(vm[g]));
    }
    __syncthreads();
    if (t < 32) bvmax[(size_t)blockIdx.x * 32 + t] = __uint_as_float(svm[t]);
}

// Pass 3: per-row loss terms -> per-block partial sums (plain stores, no atomics).
template <bool USEBITS>
__global__ void __launch_bounds__(BLK) k_pass3(const unsigned int* __restrict__ maskbits,
                                               const int* __restrict__ boxes,
                                               const float* __restrict__ scores,
                                               const float* __restrict__ ious,
                                               const float* __restrict__ logits,
                                               const float* __restrict__ conf,
                                               const float* __restrict__ vmax,
                                               float* __restrict__ partial, int n) {
    __shared__ float scf[32], srv[32];
    __shared__ float swsum[BLK / 64];
    const int t = threadIdx.x;
    if (t < 32) {
        scf[t] = conf[t];
        srv[t] = 1.0f / (vmax[t] + CLAMP_);
    }
    __syncthreads();
    float cf[32], rv[32];
#pragma unroll
    for (int g = 0; g < 32; ++g) {
        cf[g] = scf[g];
        rv[g] = srv[g];
    }
    float accpos = 0.0f;  // sum of logp*sum1 + log1mp*sum2  (scaled by -ALPHA later)
    float accneg = 0.0f;  // sum of -log(1-p)*p^2 over empty rows (scaled by 1-ALPHA)
    const size_t stride = (size_t)gridDim.x * BLK;
    for (size_t i = (size_t)blockIdx.x * BLK + t; i < (size_t)n; i += stride) {
        unsigned int m = USEBITS ? maskbits[i] : mask_from_row(boxes, i);
        float x = logits[i];
        float p = 1.0f / (1.0f + __expf(-x));
        p = fminf(fmaxf(p, CLAMP_), 1.0f - CLAMP_);
        float qq = 1.0f - p;
        float log1mp = __logf(qq);
        if (m == 0u) {
            accneg += -log1mp * p * p;
        } else {
            float logp = __logf(p);
            float ls = __logf(scores[i]);
            float iou = ious[i];
            float sum1 = 0.0f, sum2 = 0.0f;
#pragma unroll
            for (int g = 0; g < 32; ++g) {
                float val = __expf(cf[g] * ls) * iou;
                float w = (val + CLAMP_) * rv[g];
                w = fminf(fmaxf(w, CLAMP_), 1.0f - CLAMP_);
                float a = w * qq;
                float b = (1.0f - w) * p;
                bool on = (m >> g) & 1u;
                sum1 += on ? a * a : 0.0f;
                sum2 += on ? b * b : 0.0f;
            }
            accpos += logp * sum1 + log1mp * sum2;
        }
    }
    float tot = (1.0f - ALPHA_) * accneg - ALPHA_ * accpos;
#pragma unroll
    for (int off = 32; off > 0; off >>= 1) tot += __shfl_xor(tot, off);
    if ((t & 63) == 0) swsum[t >> 6] = tot;
    __syncthreads();
    if (t == 0) {
        float s = 0.0f;
#pragma unroll
        for (int w = 0; w < BLK / 64; ++w) s += swsum[w];
        partial[blockIdx.x] = s;
    }
}

__global__ void __launch_bounds__(BLK) k_fin(const float* __restrict__ partial, int nb,
                                             const unsigned int* __restrict__ npos_raw,
                                             float* __restrict__ out) {
    __shared__ float sw[BLK / 64];
    const int t = threadIdx.x;
    float s = 0.0f;
    for (int i = t; i < nb; i += BLK) s += partial[i];
#pragma unroll
    for (int off = 32; off > 0; off >>= 1) s += __shfl_xor(s, off);
    if ((t & 63) == 0) sw[t >> 6] = s;
    __syncthreads();
    if (t == 0) {
        float tot = 0.0f;
#pragma unroll
        for (int w = 0; w < BLK / 64; ++w) tot += sw[w];
        unsigned int v = *npos_raw;
        // num_pos_avg: int32 if exponent bits clear (small int), else float32 bits
        float np = (v & 0x7f800000u) ? __uint_as_float(v) : (float)(int)v;
        out[0] = tot / np;
    }
}

extern "C" void kernel_launch(void* const* d_in, const int* in_sizes, int n_in,
                              void* d_out, int out_size, void* d_ws, size_t ws_size,
                              hipStream_t stream) {
    const float* logits = (const float*)d_in[0];
    const float* scores = (const float*)d_in[1];
    const float* ious = (const float*)d_in[2];
    const int* boxes = (const int*)d_in[3];
    // d_in[4] = gt_labels (all zeros; scores/IoUMap have a single column) -> ignored
    const unsigned int* npos_raw = (const unsigned int*)d_in[5];
    float* out = (float*)d_out;
    const int n = in_sizes[0];
    const size_t total4 = (size_t)n * 8;  // flat int4 count of is_in_boxes

    unsigned char* ws = (unsigned char*)d_ws;
    float* bconf = (float*)(ws + OFF_BCONF);
    float* bvmax = (float*)(ws + OFF_BVMAX);
    float* conf = (float*)(ws + OFF_CONF);
    float* vmax = (float*)(ws + OFF_VMAX);
    float* partial = (float*)(ws + OFF_PART);
    unsigned int* maskbits = (unsigned int*)(ws + OFF_BITS);
    const bool usebits = ws_size >= OFF_BITS + (size_t)n * 4u;

    int nbfull = (n + BLK - 1) / BLK;
    int nb = nbfull < MAXB ? nbfull : MAXB;
    int nb1full = (int)((total4 + BLK - 1) / BLK);
    int nb1 = nb1full < MAXB ? nb1full : MAXB;

    if (usebits) {
        k_pass1<true><<<dim3(nb1), dim3(BLK), 0, stream>>>((const int4*)boxes, scores, maskbits,
                                                           bconf, total4);
        k_redmax<<<dim3(1), dim3(BLK), 0, stream>>>(bconf, conf, nb1);
        k_pass2<true><<<dim3(nb), dim3(BLK), 0, stream>>>(maskbits, boxes, scores, ious, conf,
                                                          bvmax, n);
        k_redmax<<<dim3(1), dim3(BLK), 0, stream>>>(bvmax, vmax, nb);
        k_pass3<true><<<dim3(nb), dim3(BLK), 0, stream>>>(maskbits, boxes, scores, ious, logits,
                                                          conf, vmax, partial, n);
    } else {
        k_pass1<false><<<dim3(nb1), dim3(BLK), 0, stream>>>((const int4*)boxes, scores, maskbits,
                                                            bconf, total4);
        k_redmax<<<dim3(1), dim3(BLK), 0, stream>>>(bconf, conf, nb1);
        k_pass2<false><<<dim3(nb), dim3(BLK), 0, stream>>>(maskbits, boxes, scores, ious, conf,
                                                           bvmax, n);
        k_redmax<<<dim3(1), dim3(BLK), 0, stream>>>(bvmax, vmax, nb);
        k_pass3<false><<<dim3(nb), dim3(BLK), 0, stream>>>(maskbits, boxes, scores, ious, logits,
                                                           conf, vmax, partial, n);
    }
    k_fin<<<dim3(1), dim3(BLK), 0, stream>>>(partial, nb, npos_raw, out);
}

// Round 5
// 81.815 us; speedup vs baseline: 1.9273x; 1.9273x over previous
//
#include <hip/hip_runtime.h>
#include <cstdint>
#include <cstddef>

#define ALPHA_ 0.25f
#define CLAMP_ 1e-4f

static constexpr int BLK = 256;
static constexpr int MAXB = 2048;

// ws layout (bytes). Every region is written before it is read on every call,
// so no initialization kernel is needed (poison-safe).
// Block partials are stored TRANSPOSED (column-major: [32][MAXB]) so the
// 32-block parallel reducer reads each column contiguously.
static constexpr size_t OFF_BCONF = 0;        // bconfT[32][MAXB] f32 (256 KB)
static constexpr size_t OFF_BVMAX = 262144;   // bvmaxT[32][MAXB] f32 (256 KB)
static constexpr size_t OFF_CONF = 524288;    // conf[32] f32
static constexpr size_t OFF_VMAX = 524416;    // vmax[32] f32
static constexpr size_t OFF_PART = 524544;    // partial[MAXB] f32 (8 KB)
static constexpr size_t OFF_BITS = 1048576;   // maskbits[N] u32 (4 MB @ N=1e6)

__device__ inline unsigned int mask_from_row(const int* __restrict__ boxes, size_t i) {
    const int4* row = (const int4*)(boxes + i * 32);
    unsigned int m = 0u;
#pragma unroll
    for (int q = 0; q < 8; ++q) {
        int4 v = row[q];
        m |= (v.x > 0 ? 1u : 0u) << (4 * q + 0);
        m |= (v.y > 0 ? 1u : 0u) << (4 * q + 1);
        m |= (v.z > 0 ? 1u : 0u) << (4 * q + 2);
        m |= (v.w > 0 ? 1u : 0u) << (4 * q + 3);
    }
    return m;
}

// Pass 1: flat, fully-coalesced int4 stream over boxes. Lane group of 8 covers one
// row; 3 shfl_xor OR-steps assemble the row's 32-bit mask; thread keeps max for its
// 4 fixed columns only (4 VGPRs).
#define PROC1(a, s, idx, act)                                                     \
    {                                                                             \
        unsigned int nib = (unsigned int)((a).x > 0) |                            \
                           ((unsigned int)((a).y > 0) << 1) |                     \
                           ((unsigned int)((a).z > 0) << 2) |                     \
                           ((unsigned int)((a).w > 0) << 3);                      \
        unsigned int mm = nib << (4 * q);                                         \
        mm |= (unsigned int)__shfl_xor((int)mm, 1);                               \
        mm |= (unsigned int)__shfl_xor((int)mm, 2);                               \
        mm |= (unsigned int)__shfl_xor((int)mm, 4);                               \
        if (WRITEBITS && (act) && q == 0) maskbits[(idx) >> 3] = mm;              \
        c0 = fmaxf(c0, (nib & 1u) ? (s) : 0.0f);                                 \
        c1 = fmaxf(c1, (nib & 2u) ? (s) : 0.0f);                                 \
        c2 = fmaxf(c2, (nib & 4u) ? (s) : 0.0f);                                 \
        c3 = fmaxf(c3, (nib & 8u) ? (s) : 0.0f);                                 \
    }

template <bool WRITEBITS>
__global__ void __launch_bounds__(BLK) k_pass1(const int4* __restrict__ boxes4,
                                               const float* __restrict__ scores,
                                               unsigned int* __restrict__ maskbits,
                                               float* __restrict__ bconfT, size_t total4) {
    __shared__ unsigned int sconf[32];
    const int t = threadIdx.x;
    if (t < 32) sconf[t] = 0u;
    __syncthreads();
    const int lane = t & 63;
    const int q = lane & 7;  // this thread owns columns 4q..4q+3
    float c0 = 0.0f, c1 = 0.0f, c2 = 0.0f, c3 = 0.0f;
    const size_t stride = (size_t)gridDim.x * BLK;
    size_t wb = (size_t)blockIdx.x * BLK + (size_t)(t - lane);  // wave-uniform base
    // main: 4 wave-iterations per trip, all lanes active -> 8 loads in flight
    for (; wb + 3 * stride + 64 <= total4; wb += 4 * stride) {
        const size_t i0 = wb + lane, i1 = i0 + stride, i2 = i1 + stride, i3 = i2 + stride;
        int4 a0 = boxes4[i0];
        int4 a1 = boxes4[i1];
        int4 a2 = boxes4[i2];
        int4 a3 = boxes4[i3];
        float s0 = scores[i0 >> 3];
        float s1 = scores[i1 >> 3];
        float s2 = scores[i2 >> 3];
        float s3 = scores[i3 >> 3];
        PROC1(a0, s0, i0, true)
        PROC1(a1, s1, i1, true)
        PROC1(a2, s2, i2, true)
        PROC1(a3, s3, i3, true)
    }
    // tail: predicated lanes, wave-uniform trip count
    for (; wb < total4; wb += stride) {
        const size_t i = wb + lane;
        const bool act = i < total4;
        int4 a = {0, 0, 0, 0};
        float s = 0.0f;
        if (act) {
            a = boxes4[i];
            s = scores[i >> 3];
        }
        PROC1(a, s, i, act)
    }
    // butterfly across the 8 row-groups in the wave (partners share q)
#pragma unroll
    for (int off = 8; off < 64; off <<= 1) {
        c0 = fmaxf(c0, __shfl_xor(c0, off));
        c1 = fmaxf(c1, __shfl_xor(c1, off));
        c2 = fmaxf(c2, __shfl_xor(c2, off));
        c3 = fmaxf(c3, __shfl_xor(c3, off));
    }
    if (lane < 8) {  // q == lane
        atomicMax(&sconf[4 * q + 0], __float_as_uint(c0));
        atomicMax(&sconf[4 * q + 1], __float_as_uint(c1));
        atomicMax(&sconf[4 * q + 2], __float_as_uint(c2));
        atomicMax(&sconf[4 * q + 3], __float_as_uint(c3));
    }
    __syncthreads();
    if (t < 32) bconfT[(size_t)t * MAXB + blockIdx.x] = __uint_as_float(sconf[t]);
}

// Parallel reducer: 32 blocks, block g reduces contiguous srcT[g][0..nb) -> dst[g].
// 256 threads/block, ~8 independent loads each -> latency fully hidden.
__global__ void __launch_bounds__(BLK) k_redmax(const float* __restrict__ srcT,
                                                float* __restrict__ dst, int nb) {
    __shared__ float sw[BLK / 64];
    const int g = blockIdx.x;
    const int t = threadIdx.x;
    const float* col = srcT + (size_t)g * MAXB;
    float m = 0.0f;  // all values >= 0
    for (int j = t; j < nb; j += BLK) m = fmaxf(m, col[j]);
#pragma unroll
    for (int off = 32; off > 0; off >>= 1) m = fmaxf(m, __shfl_xor(m, off));
    if ((t & 63) == 0) sw[t >> 6] = m;
    __syncthreads();
    if (t == 0) dst[g] = fmaxf(fmaxf(sw[0], sw[1]), fmaxf(sw[2], sw[3]));
}

// Pass 2: vmax[g] = max over masked i of exp(conf[g]*log(s_i)) * iou_i.
template <bool USEBITS>
__global__ void __launch_bounds__(BLK) k_pass2(const unsigned int* __restrict__ maskbits,
                                               const int* __restrict__ boxes,
                                               const float* __restrict__ scores,
                                               const float* __restrict__ ious,
                                               const float* __restrict__ conf,
                                               float* __restrict__ bvmaxT, int n) {
    __shared__ float scf[32];
    __shared__ unsigned int svm[32];
    const int t = threadIdx.x;
    if (t < 32) {
        scf[t] = conf[t];
        svm[t] = 0u;
    }
    __syncthreads();
    float cf[32], vm[32];
#pragma unroll
    for (int g = 0; g < 32; ++g) {
        cf[g] = scf[g];
        vm[g] = 0.0f;
    }
    const size_t stride = (size_t)gridDim.x * BLK;
    for (size_t i = (size_t)blockIdx.x * BLK + t; i < (size_t)n; i += stride) {
        unsigned int m = USEBITS ? maskbits[i] : mask_from_row(boxes, i);
        float ls = __logf(scores[i]);
        float iou = ious[i];
#pragma unroll
        for (int g = 0; g < 32; ++g) {
            float v = __expf(cf[g] * ls) * iou;
            vm[g] = fmaxf(vm[g], ((m >> g) & 1u) ? v : 0.0f);
        }
    }
    // one butterfly per thread (not per row)
#pragma unroll
    for (int g = 0; g < 32; ++g) {
#pragma unroll
        for (int off = 32; off > 0; off >>= 1) vm[g] = fmaxf(vm[g], __shfl_xor(vm[g], off));
    }
    if ((t & 63) == 0) {
#pragma unroll
        for (int g = 0; g < 32; ++g) atomicMax(&svm[g], __float_as_uint(vm[g]));
    }
    __syncthreads();
    if (t < 32) bvmaxT[(size_t)t * MAXB + blockIdx.x] = __uint_as_float(svm[t]);
}

// Pass 3: per-row loss terms -> per-block partial sums (plain stores, no atomics).
template <bool USEBITS>
__global__ void __launch_bounds__(BLK) k_pass3(const unsigned int* __restrict__ maskbits,
                                               const int* __restrict__ boxes,
                                               const float* __restrict__ scores,
                                               const float* __restrict__ ious,
                                               const float* __restrict__ logits,
                                               const float* __restrict__ conf,
                                               const float* __restrict__ vmax,
                                               float* __restrict__ partial, int n) {
    __shared__ float scf[32], srv[32];
    __shared__ float swsum[BLK / 64];
    const int t = threadIdx.x;
    if (t < 32) {
        scf[t] = conf[t];
        srv[t] = 1.0f / (vmax[t] + CLAMP_);
    }
    __syncthreads();
    float cf[32], rv[32];
#pragma unroll
    for (int g = 0; g < 32; ++g) {
        cf[g] = scf[g];
        rv[g] = srv[g];
    }
    float accpos = 0.0f;  // sum of logp*sum1 + log1mp*sum2  (scaled by -ALPHA later)
    float accneg = 0.0f;  // sum of -log(1-p)*p^2 over empty rows (scaled by 1-ALPHA)
    const size_t stride = (size_t)gridDim.x * BLK;
    for (size_t i = (size_t)blockIdx.x * BLK + t; i < (size_t)n; i += stride) {
        unsigned int m = USEBITS ? maskbits[i] : mask_from_row(boxes, i);
        float x = logits[i];
        float p = 1.0f / (1.0f + __expf(-x));
        p = fminf(fmaxf(p, CLAMP_), 1.0f - CLAMP_);
        float qq = 1.0f - p;
        float log1mp = __logf(qq);
        if (m == 0u) {
            accneg += -log1mp * p * p;
        } else {
            float logp = __logf(p);
            float ls = __logf(scores[i]);
            float iou = ious[i];
            float sum1 = 0.0f, sum2 = 0.0f;
#pragma unroll
            for (int g = 0; g < 32; ++g) {
                float val = __expf(cf[g] * ls) * iou;
                float w = (val + CLAMP_) * rv[g];
                w = fminf(fmaxf(w, CLAMP_), 1.0f - CLAMP_);
                float a = w * qq;
                float b = (1.0f - w) * p;
                bool on = (m >> g) & 1u;
                sum1 += on ? a * a : 0.0f;
                sum2 += on ? b * b : 0.0f;
            }
            accpos += logp * sum1 + log1mp * sum2;
        }
    }
    float tot = (1.0f - ALPHA_) * accneg - ALPHA_ * accpos;
#pragma unroll
    for (int off = 32; off > 0; off >>= 1) tot += __shfl_xor(tot, off);
    if ((t & 63) == 0) swsum[t >> 6] = tot;
    __syncthreads();
    if (t == 0) {
        float s = 0.0f;
#pragma unroll
        for (int w = 0; w < BLK / 64; ++w) s += swsum[w];
        partial[blockIdx.x] = s;
    }
}

__global__ void __launch_bounds__(BLK) k_fin(const float* __restrict__ partial, int nb,
                                             const unsigned int* __restrict__ npos_raw,
                                             float* __restrict__ out) {
    __shared__ float sw[BLK / 64];
    const int t = threadIdx.x;
    float s = 0.0f;
    for (int i = t; i < nb; i += BLK) s += partial[i];
#pragma unroll
    for (int off = 32; off > 0; off >>= 1) s += __shfl_xor(s, off);
    if ((t & 63) == 0) sw[t >> 6] = s;
    __syncthreads();
    if (t == 0) {
        float tot = 0.0f;
#pragma unroll
        for (int w = 0; w < BLK / 64; ++w) tot += sw[w];
        unsigned int v = *npos_raw;
        // num_pos_avg: int32 if exponent bits clear (small int), else float32 bits
        float np = (v & 0x7f800000u) ? __uint_as_float(v) : (float)(int)v;
        out[0] = tot / np;
    }
}

extern "C" void kernel_launch(void* const* d_in, const int* in_sizes, int n_in,
                              void* d_out, int out_size, void* d_ws, size_t ws_size,
                              hipStream_t stream) {
    const float* logits = (const float*)d_in[0];
    const float* scores = (const float*)d_in[1];
    const float* ious = (const float*)d_in[2];
    const int* boxes = (const int*)d_in[3];
    // d_in[4] = gt_labels (all zeros; scores/IoUMap have a single column) -> ignored
    const unsigned int* npos_raw = (const unsigned int*)d_in[5];
    float* out = (float*)d_out;
    const int n = in_sizes[0];
    const size_t total4 = (size_t)n * 8;  // flat int4 count of is_in_boxes

    unsigned char* ws = (unsigned char*)d_ws;
    float* bconfT = (float*)(ws + OFF_BCONF);
    float* bvmaxT = (float*)(ws + OFF_BVMAX);
    float* conf = (float*)(ws + OFF_CONF);
    float* vmax = (float*)(ws + OFF_VMAX);
    float* partial = (float*)(ws + OFF_PART);
    unsigned int* maskbits = (unsigned int*)(ws + OFF_BITS);
    const bool usebits = ws_size >= OFF_BITS + (size_t)n * 4u;

    int nbfull = (n + BLK - 1) / BLK;
    int nb = nbfull < MAXB ? nbfull : MAXB;
    int nb1full = (int)((total4 + BLK - 1) / BLK);
    int nb1 = nb1full < MAXB ? nb1full : MAXB;

    if (usebits) {
        k_pass1<true><<<dim3(nb1), dim3(BLK), 0, stream>>>((const int4*)boxes, scores, maskbits,
                                                           bconfT, total4);
        k_redmax<<<dim3(32), dim3(BLK), 0, stream>>>(bconfT, conf, nb1);
        k_pass2<true><<<dim3(nb), dim3(BLK), 0, stream>>>(maskbits, boxes, scores, ious, conf,
                                                          bvmaxT, n);
        k_redmax<<<dim3(32), dim3(BLK), 0, stream>>>(bvmaxT, vmax, nb);
        k_pass3<true><<<dim3(nb), dim3(BLK), 0, stream>>>(maskbits, boxes, scores, ious, logits,
                                                          conf, vmax, partial, n);
    } else {
        k_pass1<false><<<dim3(nb1), dim3(BLK), 0, stream>>>((const int4*)boxes, scores, maskbits,
                                                            bconfT, total4);
        k_redmax<<<dim3(32), dim3(BLK), 0, stream>>>(bconfT, conf, nb1);
        k_pass2<false><<<dim3(nb), dim3(BLK), 0, stream>>>(maskbits, boxes, scores, ious, conf,
                                                           bvmaxT, n);
        k_redmax<<<dim3(32), dim3(BLK), 0, stream>>>(bvmaxT, vmax, nb);
        k_pass3<false><<<dim3(nb), dim3(BLK), 0, stream>>>(maskbits, boxes, scores, ious, logits,
                                                           conf, vmax, partial, n);
    }
    k_fin<<<dim3(1), dim3(BLK), 0, stream>>>(partial, nb, npos_raw, out);
}